// Round 14
// baseline (354.457 us; speedup 1.0000x reference)
//
#include <hip/hip_runtime.h>
#include <hip/hip_bf16.h>

typedef float f32x4 __attribute__((ext_vector_type(4)));
typedef short s16x8 __attribute__((ext_vector_type(8)));

#define EPS 1e-5f

__device__ __forceinline__ unsigned short f32_to_bf16_rne(float f) {
    unsigned u = __float_as_uint(f);
    unsigned r = u + 0x7FFFu + ((u >> 16) & 1u);
    return (unsigned short)(r >> 16);
}

// packed 2x bf16 via HW converter (RNE): lo = a, hi = b
__device__ __forceinline__ unsigned cvtpk(float a, float b) {
    unsigned d;
    asm("v_cvt_pk_bf16_f32 %0, %1, %2" : "=v"(d) : "v"(a), "v"(b));
    return d;
}

// DPP helper (compile-time ctrl), all lanes active
#define DPPF(v, c) __int_as_float(__builtin_amdgcn_update_dpp(0, __float_as_int(v), (c), 0xF, 0xF, true))
// ds_swizzle xor4 (BitMode: and=0x1F, or=0, xor=4)
#define SWZ4(v) __int_as_float(__builtin_amdgcn_ds_swizzle(__float_as_int(v), 0x101F))

// ---------------- weight packing (stats-independent ones) + buffer zeroing ----------------
// pw layout (ushort, 4096 each): [0]=W1xi  [4096]=W1xj  [8192]=W1b
//                                [12288]=W2xi' [16384]=W2xj' (filled by repack2)  [20480]=W2b
__global__ void pack_zero(const float* __restrict__ W1a, const float* __restrict__ W1b,
                          const float* __restrict__ W2b, unsigned short* __restrict__ p,
                          float* __restrict__ stats, int* __restrict__ count, int N) {
    int idx = blockIdx.x * 256 + threadIdx.x;
    if (idx < 16384) {
        int m = idx >> 12;
        int t = idx & 4095;
        int j = t & 7;
        int lane = (t >> 3) & 63;
        int mt = (t >> 9) & 3;
        int kc = t >> 11;
        int k = kc * 32 + (lane >> 4) * 8 + j;
        int c = mt * 16 + (lane & 15);
        float v;
        int dst;
        switch (m) {
            case 0: v = W1a[k * 64 + c] - W1a[(k + 64) * 64 + c]; dst = t; break;
            case 1: v = W1a[(k + 64) * 64 + c]; dst = 4096 + t; break;
            case 2: v = W1b[k * 64 + c]; dst = 8192 + t; break;
            default: v = W2b[k * 64 + c]; dst = 20480 + t; break;
        }
        p[dst] = f32_to_bf16_rne(v);
    } else if (idx < 16640) {
        stats[idx - 16384] = 0.f;
    } else if (idx - 16640 < N) {
        count[idx - 16640] = 0;
    }
}

// ---------------- f32 -> bf16 table convert + dst histogram ----------------
__global__ void cvt_hist(const float* __restrict__ in, unsigned short* __restrict__ out, int n4,
                         const int* __restrict__ edst, int* __restrict__ count, int E) {
    int i = blockIdx.x * 256 + threadIdx.x;
    if (i < n4) {
        f32x4 v = ((const f32x4*)in)[i];
        uint2 pr;
        pr.x = cvtpk(v[0], v[1]);
        pr.y = cvtpk(v[2], v[3]);
        *(uint2*)(out + i * 4) = pr;
    }
    if (i < E) atomicAdd(&count[edst[i]], 1);
}

// ---------------- two-level scan: 1024 elems/block ----------------
__global__ void scan1(const int* __restrict__ count, int* __restrict__ offsets,
                      int* __restrict__ bsums, int N) {
    __shared__ int sdata[256];
    int t = threadIdx.x;
    int base = blockIdx.x * 1024 + t * 4;
    int4 v = {0, 0, 0, 0};
    if (base + 3 < N) {
        v = *(const int4*)(count + base);
    } else {
        if (base + 0 < N) v.x = count[base + 0];
        if (base + 1 < N) v.y = count[base + 1];
        if (base + 2 < N) v.z = count[base + 2];
    }
    int s = v.x + v.y + v.z + v.w;
    sdata[t] = s;
    __syncthreads();
    for (int off = 1; off < 256; off <<= 1) {
        int u = (t >= off) ? sdata[t - off] : 0;
        __syncthreads();
        sdata[t] += u;
        __syncthreads();
    }
    int excl = sdata[t] - s;
    if (t == 255) bsums[blockIdx.x] = sdata[255];
    int o0 = excl;
    int o1 = o0 + v.x;
    int o2 = o1 + v.y;
    int o3 = o2 + v.z;
    if (base + 0 < N) offsets[base + 0] = o0;
    if (base + 1 < N) offsets[base + 1] = o1;
    if (base + 2 < N) offsets[base + 2] = o2;
    if (base + 3 < N) offsets[base + 3] = o3;
}

__global__ void scan2(int* __restrict__ bsums, int* __restrict__ offsets, int N, int nb) {
    __shared__ int sdata[256];
    int t = threadIdx.x;
    int s = (t < nb) ? bsums[t] : 0;
    sdata[t] = s;
    __syncthreads();
    for (int off = 1; off < 256; off <<= 1) {
        int u = (t >= off) ? sdata[t - off] : 0;
        __syncthreads();
        sdata[t] += u;
        __syncthreads();
    }
    if (t < nb) bsums[t] = sdata[t] - s;
    if (t == 255) offsets[N] = sdata[255];
}

__global__ void scan3(int* __restrict__ offsets, int* __restrict__ cursor,
                      const int* __restrict__ bsums, int N) {
    int i = blockIdx.x * 256 + threadIdx.x;
    if (i < N) {
        int v = offsets[i] + bsums[i >> 10];
        offsets[i] = v;
        cursor[i] = v;
    }
}

__global__ void scatter_kernel(const int* __restrict__ esrc, const int* __restrict__ edst,
                               int* __restrict__ cursor, int* __restrict__ ssrc, int E) {
    int i = blockIdx.x * 256 + threadIdx.x;
    if (i < E) {
        int d = edst[i];
        int pos = atomicAdd(&cursor[d], 1);
        ssrc[pos] = esrc[i];
    }
}

// ---------------- BN1 fold: repack layer-2 first-matmul weights + bias ----------------
__global__ void repack2(const float* __restrict__ stats, const float* __restrict__ gamma1,
                        const float* __restrict__ beta1, const float* __restrict__ W2a,
                        const float* __restrict__ b2a, unsigned short* __restrict__ pw2,
                        float* __restrict__ b2adj, float invN) {
    __shared__ float sc[64], sh[64];
    __shared__ float part[4][64];
    int tid = threadIdx.x;
    if (tid < 64) {
        float mean = stats[tid] * invN;
        float var = stats[64 + tid] * invN - mean * mean;
        float s = gamma1[tid] * rsqrtf(var + EPS);
        sc[tid] = s;
        sh[tid] = beta1[tid] - mean * s;
    }
    __syncthreads();
    if (blockIdx.x == 0) {
        int c = tid & 63, sl = tid >> 6;
        float a = 0.f;
#pragma unroll
        for (int kk = 0; kk < 16; ++kk) {
            int k = sl * 16 + kk;
            a += sh[k] * W2a[k * 64 + c];
        }
        part[sl][c] = a;
        __syncthreads();
        if (tid < 64)
            b2adj[tid] = b2a[tid] + part[0][tid] + part[1][tid] + part[2][tid] + part[3][tid];
    }

    for (int e = blockIdx.x * 256 + tid; e < 8192; e += 16 * 256) {
        int m = e >> 12;  // 0: Wxi', 1: Wxj'
        int t = e & 4095;
        int j = t & 7;
        int lane = (t >> 3) & 63;
        int mt = (t >> 9) & 3;
        int kc = t >> 11;
        int k = kc * 32 + (lane >> 4) * 8 + j;
        int c = mt * 16 + (lane & 15);
        float wtop = W2a[k * 64 + c];
        float wbot = W2a[(k + 64) * 64 + c];
        float v = (m == 0) ? sc[k] * (wtop - wbot) : sc[k] * wbot;
        pw2[e] = f32_to_bf16_rne(v);
    }
}

// ---------------- fused EdgeConv on dst-sorted edges, two nodes per wave ----------------
// Weights in block-shared LDS (R12) frees ~64 VGPR -> room for TWO interleaved
// per-node dependency chains (R9's idea, which spilled then at VGPR 84 base;
// base is now 60). Straight-line joint tile loop with clamped indices: the
// shorter node redundantly re-does its last tile (idempotent under max).
#define LSTR 72  // LDS row stride in ushorts
__global__ __launch_bounds__(256, 3) void edgeconv_sorted(
    const unsigned short* __restrict__ xb,   // [N][64] bf16 gather table
    const int* __restrict__ ssrc,            // [E] src idx sorted by dst
    const int* __restrict__ offsets,         // [N+1]
    const unsigned short* __restrict__ pW,   // packed [3][4096]: Wxi, Wxj, Wb
    const float* __restrict__ ba,
    const float* __restrict__ bb,
    float* __restrict__ outf,                // f32 [N][64] or null
    unsigned short* __restrict__ outb,       // bf16 [N][64] or null
    float* __restrict__ statsOut,            // [128] sum/sumsq accumulators
    int N) {
    __shared__ __align__(16) unsigned short lw[12288];              // Wxi|Wxj|Wb
    __shared__ __align__(16) unsigned short xh[4][2 * 16 * LSTR];   // A,B buffers
    __shared__ float sred[128];
    const int tid = threadIdx.x;
    const int w = tid >> 6;
    const int lane = tid & 63;
    const int g = lane >> 4;
    const int r = lane & 15;
    const int srow = lane >> 2;
    const int schk = lane & 3;

    // cooperative weight copy global -> LDS (1536 x 16B)
    for (int i = tid; i < 1536; i += 256)
        ((s16x8*)lw)[i] = ((const s16x8*)pW)[i];
    if (tid < 128) sred[tid] = 0.f;
    __syncthreads();

    const unsigned short* wxi = lw;
    const unsigned short* wxj = lw + 4096;
    const unsigned short* wb = lw + 8192;

    unsigned short* mybA = xh[w];
    unsigned short* mybB = xh[w] + 16 * LSTR;
    const int totalWaves = gridDim.x * 4;
    const int stride2 = totalWaves * 2;
    const f32x4 zf = {0.f, 0.f, 0.f, 0.f};

    const int ch = (r >> 2) * 16 + g * 4 + (r & 3);
    const float b2l = bb[ch];
    float bsum = 0.f, bss = 0.f;

    for (int nA = blockIdx.x * 4 + w; nA < N; nA += stride2) {
        const int nB = nA + totalWaves;
        const bool hasB = nB < N;
        const int rowB = hasB ? nB : nA;

        const int sBA = offsets[nA];
        const int sEA = offsets[nA + 1];
        int sBB = sBA, sEB = sEA;
        if (hasB) {
            sBB = offsets[nB];
            sEB = offsets[nB + 1];
        }
        const bool vA = sEA > sBA;
        const bool vB = hasB && (sEB > sBB);
        const int ntA = vA ? (sEA - sBA + 15) >> 4 : 1;
        const int ntB = vB ? (sEB - sBB + 15) >> 4 : 1;
        const int nt = max(ntA, ntB);

        // prime tile-0 gathers for both nodes (clamped-safe)
        int ivA = max(min(sBA + srow, sEA - 1), 0);
        int ivB = max(min(sBB + srow, sEB - 1), 0);
        int svA = ssrc[ivA];
        int svB = ssrc[ivB];
        s16x8 raA = *(const s16x8*)(xb + svA * 64 + schk * 8);
        s16x8 rbA = *(const s16x8*)(xb + svA * 64 + 32 + schk * 8);
        s16x8 raB = *(const s16x8*)(xb + svB * 64 + schk * 8);
        s16x8 rbB = *(const s16x8*)(xb + svB * 64 + 32 + schk * 8);

        // xi-part + bias for both nodes (two independent MFMA chains)
        s16x8 xiA1 = *(const s16x8*)(xb + nA * 64 + g * 8);
        s16x8 xiA2 = *(const s16x8*)(xb + nA * 64 + 32 + g * 8);
        s16x8 xiB1 = *(const s16x8*)(xb + rowB * 64 + g * 8);
        s16x8 xiB2 = *(const s16x8*)(xb + rowB * 64 + 32 + g * 8);
        f32x4 accxiA[4], accxiB[4];
#pragma unroll
        for (int mt = 0; mt < 4; ++mt) {
            f32x4 bias = *(const f32x4*)(ba + mt * 16 + g * 4);
            s16x8 f0 = *(const s16x8*)(wxi + ((0 * 4 + mt) * 64 + lane) * 8);
            s16x8 f1 = *(const s16x8*)(wxi + ((1 * 4 + mt) * 64 + lane) * 8);
            f32x4 cA = __builtin_amdgcn_mfma_f32_16x16x32_bf16(f0, xiA1, bias, 0, 0, 0);
            f32x4 cB = __builtin_amdgcn_mfma_f32_16x16x32_bf16(f0, xiB1, bias, 0, 0, 0);
            accxiA[mt] = __builtin_amdgcn_mfma_f32_16x16x32_bf16(f1, xiA2, cA, 0, 0, 0);
            accxiB[mt] = __builtin_amdgcn_mfma_f32_16x16x32_bf16(f1, xiB2, cB, 0, 0, 0);
        }

        f32x4 rmA[4], rmB[4];
#pragma unroll
        for (int mt = 0; mt < 4; ++mt) {
            rmA[mt] = (f32x4){-INFINITY, -INFINITY, -INFINITY, -INFINITY};
            rmB[mt] = (f32x4){-INFINITY, -INFINITY, -INFINITY, -INFINITY};
        }

        for (int it = 0; it < nt; ++it) {
            // stage both tiles (per-wave LDS: in-order, no barrier)
            *(s16x8*)(mybA + srow * LSTR + schk * 8) = raA;
            *(s16x8*)(mybA + srow * LSTR + 32 + schk * 8) = rbA;
            *(s16x8*)(mybB + srow * LSTR + schk * 8) = raB;
            *(s16x8*)(mybB + srow * LSTR + 32 + schk * 8) = rbB;
            s16x8 xjA1 = *(const s16x8*)(mybA + r * LSTR + g * 8);
            s16x8 xjA2 = *(const s16x8*)(mybA + r * LSTR + 32 + g * 8);
            s16x8 xjB1 = *(const s16x8*)(mybB + r * LSTR + g * 8);
            s16x8 xjB2 = *(const s16x8*)(mybB + r * LSTR + 32 + g * 8);

            // prefetch next tiles (clamped: exhausted node re-reads its last tile)
            if (it + 1 < nt) {
                int tA2 = sBA + 16 * min(it + 1, ntA - 1);
                int tB2 = sBB + 16 * min(it + 1, ntB - 1);
                int iA2 = max(min(tA2 + srow, sEA - 1), 0);
                int iB2 = max(min(tB2 + srow, sEB - 1), 0);
                svA = ssrc[iA2];
                svB = ssrc[iB2];
                raA = *(const s16x8*)(xb + svA * 64 + schk * 8);
                rbA = *(const s16x8*)(xb + svA * 64 + 32 + schk * 8);
                raB = *(const s16x8*)(xb + svB * 64 + schk * 8);
                rbB = *(const s16x8*)(xb + svB * 64 + 32 + schk * 8);
            }

            // layer 1 both nodes (C-init = xi-part + bias); Wxj from LDS
            f32x4 accA[4], accB[4];
#pragma unroll
            for (int mt = 0; mt < 4; ++mt) {
                s16x8 a0 = *(const s16x8*)(wxj + ((0 * 4 + mt) * 64 + lane) * 8);
                accA[mt] = __builtin_amdgcn_mfma_f32_16x16x32_bf16(a0, xjA1, accxiA[mt], 0, 0, 0);
                accB[mt] = __builtin_amdgcn_mfma_f32_16x16x32_bf16(a0, xjB1, accxiB[mt], 0, 0, 0);
                s16x8 a1 = *(const s16x8*)(wxj + ((1 * 4 + mt) * 64 + lane) * 8);
                accA[mt] = __builtin_amdgcn_mfma_f32_16x16x32_bf16(a1, xjA2, accA[mt], 0, 0, 0);
                accB[mt] = __builtin_amdgcn_mfma_f32_16x16x32_bf16(a1, xjB2, accB[mt], 0, 0, 0);
            }

            // relu + bf16 pack, bounce through LDS (buffers reused, in-order DS)
#pragma unroll
            for (int mt = 0; mt < 4; ++mt) {
                uint2 prA, prB;
                prA.x = cvtpk(fmaxf(accA[mt][0], 0.f), fmaxf(accA[mt][1], 0.f));
                prA.y = cvtpk(fmaxf(accA[mt][2], 0.f), fmaxf(accA[mt][3], 0.f));
                *(uint2*)(mybA + r * LSTR + mt * 16 + g * 4) = prA;
                prB.x = cvtpk(fmaxf(accB[mt][0], 0.f), fmaxf(accB[mt][1], 0.f));
                prB.y = cvtpk(fmaxf(accB[mt][2], 0.f), fmaxf(accB[mt][3], 0.f));
                *(uint2*)(mybB + r * LSTR + mt * 16 + g * 4) = prB;
            }
            s16x8 pA0 = *(const s16x8*)(mybA + r * LSTR + g * 8);
            s16x8 pA1 = *(const s16x8*)(mybA + r * LSTR + 32 + g * 8);
            s16x8 pB0 = *(const s16x8*)(mybB + r * LSTR + g * 8);
            s16x8 pB1 = *(const s16x8*)(mybB + r * LSTR + 32 + g * 8);

            // layer 2 both nodes; Wb from LDS
            f32x4 acc2A[4], acc2B[4];
#pragma unroll
            for (int mt = 0; mt < 4; ++mt) {
                s16x8 b0 = *(const s16x8*)(wb + ((0 * 4 + mt) * 64 + lane) * 8);
                acc2A[mt] = __builtin_amdgcn_mfma_f32_16x16x32_bf16(b0, pA0, zf, 0, 0, 0);
                acc2B[mt] = __builtin_amdgcn_mfma_f32_16x16x32_bf16(b0, pB0, zf, 0, 0, 0);
                s16x8 b1 = *(const s16x8*)(wb + ((1 * 4 + mt) * 64 + lane) * 8);
                acc2A[mt] = __builtin_amdgcn_mfma_f32_16x16x32_bf16(b1, pA1, acc2A[mt], 0, 0, 0);
                acc2B[mt] = __builtin_amdgcn_mfma_f32_16x16x32_bf16(b1, pB1, acc2B[mt], 0, 0, 0);
            }

            // unconditional max update (clamped cols duplicate a real edge)
#pragma unroll
            for (int mt = 0; mt < 4; ++mt)
#pragma unroll
                for (int q = 0; q < 4; ++q) {
                    rmA[mt][q] = fmaxf(rmA[mt][q], acc2A[mt][q]);
                    rmB[mt][q] = fmaxf(rmB[mt][q], acc2B[mt][q]);
                }
        }

        // gate empty segments back to -inf (their tile data was garbage)
#pragma unroll
        for (int mt = 0; mt < 4; ++mt)
#pragma unroll
            for (int q = 0; q < 4; ++q) {
                rmA[mt][q] = vA ? rmA[mt][q] : -INFINITY;
                rmB[mt][q] = vB ? rmB[mt][q] : -INFINITY;
            }

        // ---- epilogue A then B: reduce-scatter -> lane r owns value r ----
#pragma unroll
        for (int nsel = 0; nsel < 2; ++nsel) {
            const f32x4* rm = nsel ? rmB : rmA;
            float k8[8];
#pragma unroll
            for (int j = 0; j < 8; ++j) {
                float lo = rm[j >> 2][j & 3];
                float hv = rm[(j >> 2) + 2][j & 3];
                float tlo = DPPF(lo, 0x128);
                float thi = DPPF(hv, 0x128);
                float own = (r & 8) ? hv : lo;
                float oth = (r & 8) ? thi : tlo;
                k8[j] = fmaxf(own, oth);
            }
            float k4[4];
#pragma unroll
            for (int j = 0; j < 4; ++j) {
                float ta = SWZ4(k8[j]);
                float tb = SWZ4(k8[j + 4]);
                float own = (r & 4) ? k8[j + 4] : k8[j];
                float oth = (r & 4) ? tb : ta;
                k4[j] = fmaxf(own, oth);
            }
            float k2[2];
#pragma unroll
            for (int j = 0; j < 2; ++j) {
                float ta = DPPF(k4[j], 0x4E);
                float tb = DPPF(k4[j + 2], 0x4E);
                float own = (r & 2) ? k4[j + 2] : k4[j];
                float oth = (r & 2) ? tb : ta;
                k2[j] = fmaxf(own, oth);
            }
            float ta = DPPF(k2[0], 0xB1);
            float tb = DPPF(k2[1], 0xB1);
            float vfin = fmaxf((r & 1) ? k2[1] : k2[0], (r & 1) ? tb : ta);

            float o = fmaxf(vfin + b2l, 0.f);
            int node = nsel ? nB : nA;
            if (!nsel || hasB) {
                if (outb)
                    outb[node * 64 + ch] = f32_to_bf16_rne(o);
                else
                    outf[node * 64 + ch] = o;
                bsum += o;
                bss += o * o;
            }
        }
    }

    // ---- fused BN stats: block LDS reduce, then 128 global atomics ----
    atomicAdd(&sred[ch], bsum);
    atomicAdd(&sred[64 + ch], bss);
    __syncthreads();
    if (tid < 128) atomicAdd(&statsOut[tid], sred[tid]);
}

// ---------------- batchnorm apply (final layer only) ----------------
__global__ void bn_apply(const float* __restrict__ in, const float* __restrict__ stats,
                         const float* __restrict__ gamma, const float* __restrict__ beta,
                         float* __restrict__ outf, int n4, float invN) {
    int i = blockIdx.x * 256 + threadIdx.x;
    if (i >= n4) return;
    int c0 = (i * 4) & 63;
    f32x4 v = ((const f32x4*)in)[i];
    f32x4 o;
#pragma unroll
    for (int q = 0; q < 4; ++q) {
        int c = c0 + q;
        float mean = stats[c] * invN;
        float var = stats[64 + c] * invN - mean * mean;
        float sc = gamma[c] * rsqrtf(var + EPS);
        o[q] = (v[q] - mean) * sc + beta[c];
    }
    ((f32x4*)outf)[i] = o;
}

extern "C" void kernel_launch(void* const* d_in, const int* in_sizes, int n_in,
                              void* d_out, int out_size, void* d_ws, size_t ws_size,
                              hipStream_t stream) {
    const float* x = (const float*)d_in[0];
    const int* ei = (const int*)d_in[1];
    // d_in[2] = batch (unused, single graph)
    const float* W1a = (const float*)d_in[3];
    const float* b1a = (const float*)d_in[4];
    const float* W1b = (const float*)d_in[5];
    const float* b1b = (const float*)d_in[6];
    const float* gamma1 = (const float*)d_in[7];
    const float* beta1 = (const float*)d_in[8];
    const float* W2a = (const float*)d_in[9];
    const float* b2a = (const float*)d_in[10];
    const float* W2b = (const float*)d_in[11];
    const float* b2b = (const float*)d_in[12];
    const float* gamma2 = (const float*)d_in[13];
    const float* beta2 = (const float*)d_in[14];

    const int N = in_sizes[0] / 64;
    const int E = in_sizes[1] / 2;
    const int NC = N * 64;

    char* ws = (char*)d_ws;
    size_t off = 0;
    auto alloc = [&](size_t bytes) {
        char* p = ws + off;
        off += (bytes + 255) & ~(size_t)255;
        return p;
    };
    unsigned short* xb1 = (unsigned short*)alloc((size_t)NC * 2);  // bf16 x table
    unsigned short* xb2 = (unsigned short*)alloc((size_t)NC * 2);  // bf16 raw h1 table
    unsigned short* pw = (unsigned short*)alloc(24576 * 2);
    float* stats = (float*)alloc(256 * 4);
    float* b2adj = (float*)alloc(64 * 4);
    int* count = (int*)alloc((size_t)N * 4);
    int* offsets = (int*)alloc((size_t)(N + 1) * 4);
    int* cursor = (int*)alloc((size_t)(N + 1) * 4);
    int* ssrc = (int*)alloc((size_t)E * 4);
    int* bsums = (int*)alloc(1024 * 4);

    const int* esrc = ei;
    const int* edst = ei + E;

    // pack stats-independent weights + zero stats/count
    int pgrid = (16640 + N + 255) / 256;
    pack_zero<<<pgrid, 256, 0, stream>>>(W1a, W1b, W2b, pw, stats, count, N);

    // bf16 table + dst histogram
    int n4 = NC / 4;
    int big = max(n4, E);
    cvt_hist<<<(big + 255) / 256, 256, 0, stream>>>(x, xb1, n4, edst, count, E);

    // two-level scan (counting sort offsets)
    int nb = (N + 1023) / 1024;
    scan1<<<nb, 256, 0, stream>>>(count, offsets, bsums, N);
    scan2<<<1, 256, 0, stream>>>(bsums, offsets, N, nb);
    scan3<<<(N + 255) / 256, 256, 0, stream>>>(offsets, cursor, bsums, N);
    scatter_kernel<<<(E + 255) / 256, 256, 0, stream>>>(esrc, edst, cursor, ssrc, E);

    const int egrid = 2048;

    // layer 1: raw post-relu output -> bf16 table xb2 (+ fused BN1 stats)
    edgeconv_sorted<<<egrid, 256, 0, stream>>>(xb1, ssrc, offsets, pw, b1a, b1b,
                                               nullptr, xb2, stats, N);

    // fold BN1 into layer-2 first matmul: scaled weights + adjusted bias (16 blocks)
    repack2<<<16, 256, 0, stream>>>(stats, gamma1, beta1, W2a, b2a, pw + 12288, b2adj, 1.0f / N);

    // layer 2: consumes raw h1 table with folded weights -> raw out (+ fused BN2 stats)
    edgeconv_sorted<<<egrid, 256, 0, stream>>>(xb2, ssrc, offsets, pw + 12288, b2adj, b2b,
                                               (float*)d_out, nullptr, stats + 128, N);

    // final BN2 normalize in place
    int cgrid = (n4 + 255) / 256;
    bn_apply<<<cgrid, 256, 0, stream>>>((float*)d_out, stats + 128, gamma2, beta2,
                                        (float*)d_out, n4, 1.0f / N);
}

// Round 15
// 298.394 us; speedup vs baseline: 1.1879x; 1.1879x over previous
//
#include <hip/hip_runtime.h>
#include <hip/hip_bf16.h>

typedef float f32x4 __attribute__((ext_vector_type(4)));
typedef short s16x8 __attribute__((ext_vector_type(8)));

#define EPS 1e-5f

__device__ __forceinline__ unsigned short f32_to_bf16_rne(float f) {
    unsigned u = __float_as_uint(f);
    unsigned r = u + 0x7FFFu + ((u >> 16) & 1u);
    return (unsigned short)(r >> 16);
}

// packed 2x bf16 via HW converter (RNE): lo = a, hi = b
__device__ __forceinline__ unsigned cvtpk(float a, float b) {
    unsigned d;
    asm("v_cvt_pk_bf16_f32 %0, %1, %2" : "=v"(d) : "v"(a), "v"(b));
    return d;
}

// DPP helper (compile-time ctrl), all lanes active
#define DPPF(v, c) __int_as_float(__builtin_amdgcn_update_dpp(0, __float_as_int(v), (c), 0xF, 0xF, true))
// ds_swizzle xor4 (BitMode: and=0x1F, or=0, xor=4)
#define SWZ4(v) __int_as_float(__builtin_amdgcn_ds_swizzle(__float_as_int(v), 0x101F))

// ---------------- weight packing (stats-independent ones) + buffer zeroing ----------------
// pw layout (ushort, 4096 each): [0]=W1xi  [4096]=W1xj  [8192]=W1b
//                                [12288]=W2xi' [16384]=W2xj' (filled by repack2)  [20480]=W2b
__global__ void pack_zero(const float* __restrict__ W1a, const float* __restrict__ W1b,
                          const float* __restrict__ W2b, unsigned short* __restrict__ p,
                          float* __restrict__ stats, int* __restrict__ count, int N) {
    int idx = blockIdx.x * 256 + threadIdx.x;
    if (idx < 16384) {
        int m = idx >> 12;
        int t = idx & 4095;
        int j = t & 7;
        int lane = (t >> 3) & 63;
        int mt = (t >> 9) & 3;
        int kc = t >> 11;
        int k = kc * 32 + (lane >> 4) * 8 + j;
        int c = mt * 16 + (lane & 15);
        float v;
        int dst;
        switch (m) {
            case 0: v = W1a[k * 64 + c] - W1a[(k + 64) * 64 + c]; dst = t; break;
            case 1: v = W1a[(k + 64) * 64 + c]; dst = 4096 + t; break;
            case 2: v = W1b[k * 64 + c]; dst = 8192 + t; break;
            default: v = W2b[k * 64 + c]; dst = 20480 + t; break;
        }
        p[dst] = f32_to_bf16_rne(v);
    } else if (idx < 16640) {
        stats[idx - 16384] = 0.f;
    } else if (idx - 16640 < N) {
        count[idx - 16640] = 0;
    }
}

// ---------------- f32 -> bf16 table convert + dst histogram ----------------
__global__ void cvt_hist(const float* __restrict__ in, unsigned short* __restrict__ out, int n4,
                         const int* __restrict__ edst, int* __restrict__ count, int E) {
    int i = blockIdx.x * 256 + threadIdx.x;
    if (i < n4) {
        f32x4 v = ((const f32x4*)in)[i];
        uint2 pr;
        pr.x = cvtpk(v[0], v[1]);
        pr.y = cvtpk(v[2], v[3]);
        *(uint2*)(out + i * 4) = pr;
    }
    if (i < E) atomicAdd(&count[edst[i]], 1);
}

// ---------------- two-level scan: 1024 elems/block ----------------
// scan1 writes BLOCK-LOCAL exclusive offsets into offsets[] and cursor[];
// scan2 makes bsums[] the exclusive block bases and writes offsets[N]=E.
// Consumers add bsums[i>>10] on the fly (scan3 eliminated).
__global__ void scan1(const int* __restrict__ count, int* __restrict__ offsets,
                      int* __restrict__ cursor, int* __restrict__ bsums, int N) {
    __shared__ int sdata[256];
    int t = threadIdx.x;
    int base = blockIdx.x * 1024 + t * 4;
    int4 v = {0, 0, 0, 0};
    if (base + 3 < N) {
        v = *(const int4*)(count + base);
    } else {
        if (base + 0 < N) v.x = count[base + 0];
        if (base + 1 < N) v.y = count[base + 1];
        if (base + 2 < N) v.z = count[base + 2];
    }
    int s = v.x + v.y + v.z + v.w;
    sdata[t] = s;
    __syncthreads();
    for (int off = 1; off < 256; off <<= 1) {
        int u = (t >= off) ? sdata[t - off] : 0;
        __syncthreads();
        sdata[t] += u;
        __syncthreads();
    }
    int excl = sdata[t] - s;
    if (t == 255) bsums[blockIdx.x] = sdata[255];
    int o0 = excl;
    int o1 = o0 + v.x;
    int o2 = o1 + v.y;
    int o3 = o2 + v.z;
    if (base + 0 < N) { offsets[base + 0] = o0; cursor[base + 0] = o0; }
    if (base + 1 < N) { offsets[base + 1] = o1; cursor[base + 1] = o1; }
    if (base + 2 < N) { offsets[base + 2] = o2; cursor[base + 2] = o2; }
    if (base + 3 < N) { offsets[base + 3] = o3; cursor[base + 3] = o3; }
}

__global__ void scan2(int* __restrict__ bsums, int* __restrict__ offsets, int N, int nb) {
    __shared__ int sdata[256];
    int t = threadIdx.x;
    int s = (t < nb) ? bsums[t] : 0;
    sdata[t] = s;
    __syncthreads();
    for (int off = 1; off < 256; off <<= 1) {
        int u = (t >= off) ? sdata[t - off] : 0;
        __syncthreads();
        sdata[t] += u;
        __syncthreads();
    }
    if (t < nb) bsums[t] = sdata[t] - s;  // exclusive block base
    if (t == 255) offsets[N] = sdata[255];  // global total (=E), no bsums add
}

__global__ void scatter_kernel(const int* __restrict__ esrc, const int* __restrict__ edst,
                               int* __restrict__ cursor, const int* __restrict__ bsums,
                               int* __restrict__ ssrc, int E) {
    int i = blockIdx.x * 256 + threadIdx.x;
    if (i < E) {
        int d = edst[i];
        int pos = atomicAdd(&cursor[d], 1) + bsums[d >> 10];
        ssrc[pos] = esrc[i];
    }
}

// ---------------- BN1 fold: repack layer-2 first-matmul weights + bias ----------------
__global__ void repack2(const float* __restrict__ stats, const float* __restrict__ gamma1,
                        const float* __restrict__ beta1, const float* __restrict__ W2a,
                        const float* __restrict__ b2a, unsigned short* __restrict__ pw2,
                        float* __restrict__ b2adj, float invN) {
    __shared__ float sc[64], sh[64];
    __shared__ float part[4][64];
    int tid = threadIdx.x;
    if (tid < 64) {
        float mean = stats[tid] * invN;
        float var = stats[64 + tid] * invN - mean * mean;
        float s = gamma1[tid] * rsqrtf(var + EPS);
        sc[tid] = s;
        sh[tid] = beta1[tid] - mean * s;
    }
    __syncthreads();
    if (blockIdx.x == 0) {
        int c = tid & 63, sl = tid >> 6;
        float a = 0.f;
#pragma unroll
        for (int kk = 0; kk < 16; ++kk) {
            int k = sl * 16 + kk;
            a += sh[k] * W2a[k * 64 + c];
        }
        part[sl][c] = a;
        __syncthreads();
        if (tid < 64)
            b2adj[tid] = b2a[tid] + part[0][tid] + part[1][tid] + part[2][tid] + part[3][tid];
    }

    for (int e = blockIdx.x * 256 + tid; e < 8192; e += 16 * 256) {
        int m = e >> 12;  // 0: Wxi', 1: Wxj'
        int t = e & 4095;
        int j = t & 7;
        int lane = (t >> 3) & 63;
        int mt = (t >> 9) & 3;
        int kc = t >> 11;
        int k = kc * 32 + (lane >> 4) * 8 + j;
        int c = mt * 16 + (lane & 15);
        float wtop = W2a[k * 64 + c];
        float wbot = W2a[(k + 64) * 64 + c];
        float v = (m == 0) ? sc[k] * (wtop - wbot) : sc[k] * wbot;
        pw2[e] = f32_to_bf16_rne(v);
    }
}

// ---------------- fused EdgeConv on dst-sorted edges (R13 structure) ----------------
// Wxi/Wxj in block-shared LDS; Wb (used every tile, 8 frags) back in registers
// to relieve the DS pipe (R12 put all 24 frag-reads/tile on LDS). VGPR ~92 stays
// under the (256,4) cap; LDS drops to ~26KB -> more blocks/CU.
#define LSTR 72  // LDS row stride in ushorts
__global__ __launch_bounds__(256, 4) void edgeconv_sorted(
    const unsigned short* __restrict__ xb,    // [N][64] bf16 gather table
    const int* __restrict__ ssrc,             // [E] src idx sorted by dst
    const int* __restrict__ offsets,          // [N+1] block-local + offsets[N]=E
    const int* __restrict__ bsums,            // [nb] exclusive block bases
    const unsigned short* __restrict__ pWab,  // packed [2][4096]: Wxi, Wxj
    const unsigned short* __restrict__ pWb,   // packed [4096]: Wb
    const float* __restrict__ ba,
    const float* __restrict__ bb,
    float* __restrict__ outf,                 // f32 [N][64] or null
    unsigned short* __restrict__ outb,        // bf16 [N][64] or null
    float* __restrict__ statsOut,             // [128] sum/sumsq accumulators
    int N) {
    __shared__ __align__(16) unsigned short lw[8192];           // Wxi|Wxj
    __shared__ __align__(16) unsigned short xh[4][16 * LSTR];   // xstage/h1 aliased
    __shared__ float sred[128];
    const int tid = threadIdx.x;
    const int w = tid >> 6;
    const int lane = tid & 63;
    const int g = lane >> 4;
    const int r = lane & 15;
    const int srow = lane >> 2;  // staging: row slot this lane serves
    const int schk = lane & 3;   // staging: 16B chunk within row half

    // cooperative weight copy global -> LDS (1024 x 16B)
    for (int i = tid; i < 1024; i += 256)
        ((s16x8*)lw)[i] = ((const s16x8*)pWab)[i];
    if (tid < 128) sred[tid] = 0.f;

    // Wb fragments in registers (used every tile)
    s16x8 ab[2][4];
#pragma unroll
    for (int kc = 0; kc < 2; ++kc)
#pragma unroll
        for (int mt = 0; mt < 4; ++mt)
            ab[kc][mt] = *(const s16x8*)(pWb + ((kc * 4 + mt) * 64 + lane) * 8);
    __syncthreads();

    const unsigned short* wxi = lw;
    const unsigned short* wxj = lw + 4096;

    unsigned short* myb = xh[w];
    const int totalWaves = gridDim.x * 4;
    const f32x4 zf = {0.f, 0.f, 0.f, 0.f};

    const int ch = (r >> 2) * 16 + g * 4 + (r & 3);  // this lane's output channel
    const float b2l = bb[ch];
    float bsum = 0.f, bss = 0.f;

    for (int node = blockIdx.x * 4 + w; node < N; node += totalWaves) {
        const int segB = offsets[node] + bsums[node >> 10];
        const int np1 = node + 1;
        const int segE = offsets[np1] + ((np1 < N) ? bsums[np1 >> 10] : 0);

        f32x4 rm[4];
#pragma unroll
        for (int mt = 0; mt < 4; ++mt)
            rm[mt] = (f32x4){-INFINITY, -INFINITY, -INFINITY, -INFINITY};

        if (segB < segE) {
            // first tile prefetch (ssrc + rows) before accxi MFMA work
            int sv = ssrc[min(segB + srow, segE - 1)];
            s16x8 ra = *(const s16x8*)(xb + sv * 64 + schk * 8);
            s16x8 rb = *(const s16x8*)(xb + sv * 64 + 32 + schk * 8);

            // xi-part + bias, once per node (broadcast across the 16 columns)
            s16x8 xi1 = *(const s16x8*)(xb + node * 64 + g * 8);
            s16x8 xi2 = *(const s16x8*)(xb + node * 64 + 32 + g * 8);
            f32x4 accxi[4];
#pragma unroll
            for (int mt = 0; mt < 4; ++mt)
                accxi[mt] = *(const f32x4*)(ba + mt * 16 + g * 4);
#pragma unroll
            for (int mt = 0; mt < 4; ++mt) {
                s16x8 f0 = *(const s16x8*)(wxi + ((0 * 4 + mt) * 64 + lane) * 8);
                accxi[mt] = __builtin_amdgcn_mfma_f32_16x16x32_bf16(f0, xi1, accxi[mt], 0, 0, 0);
                s16x8 f1 = *(const s16x8*)(wxi + ((1 * 4 + mt) * 64 + lane) * 8);
                accxi[mt] = __builtin_amdgcn_mfma_f32_16x16x32_bf16(f1, xi2, accxi[mt], 0, 0, 0);
            }

            for (int t0 = segB; t0 < segE; t0 += 16) {
                // stage prefetched rows (per-wave LDS: in-order, no barrier)
                *(s16x8*)(myb + srow * LSTR + schk * 8) = ra;
                *(s16x8*)(myb + srow * LSTR + 32 + schk * 8) = rb;
                s16x8 xj1 = *(const s16x8*)(myb + r * LSTR + g * 8);
                s16x8 xj2 = *(const s16x8*)(myb + r * LSTR + 32 + g * 8);

                // within-segment prefetch of next tile
                int t1 = t0 + 16;
                if (t1 < segE) {
                    int sv2 = ssrc[min(t1 + srow, segE - 1)];
                    ra = *(const s16x8*)(xb + sv2 * 64 + schk * 8);
                    rb = *(const s16x8*)(xb + sv2 * 64 + 32 + schk * 8);
                }

                // layer 1 (C-init = xi-part + bias); Wxj frags streamed from LDS
                f32x4 acc[4];
#pragma unroll
                for (int mt = 0; mt < 4; ++mt) {
                    s16x8 a0 = *(const s16x8*)(wxj + ((0 * 4 + mt) * 64 + lane) * 8);
                    acc[mt] = __builtin_amdgcn_mfma_f32_16x16x32_bf16(a0, xj1, accxi[mt], 0, 0, 0);
                    s16x8 a1 = *(const s16x8*)(wxj + ((1 * 4 + mt) * 64 + lane) * 8);
                    acc[mt] = __builtin_amdgcn_mfma_f32_16x16x32_bf16(a1, xj2, acc[mt], 0, 0, 0);
                }

                // relu + HW bf16 pack, bounce through LDS (aliased, in-order DS)
#pragma unroll
                for (int mt = 0; mt < 4; ++mt) {
                    uint2 pr;
                    pr.x = cvtpk(fmaxf(acc[mt][0], 0.f), fmaxf(acc[mt][1], 0.f));
                    pr.y = cvtpk(fmaxf(acc[mt][2], 0.f), fmaxf(acc[mt][3], 0.f));
                    *(uint2*)(myb + r * LSTR + mt * 16 + g * 4) = pr;
                }
                s16x8 p0 = *(const s16x8*)(myb + r * LSTR + g * 8);
                s16x8 p1 = *(const s16x8*)(myb + r * LSTR + 32 + g * 8);

                // second matmul; Wb frags from registers
                f32x4 acc2[4];
#pragma unroll
                for (int mt = 0; mt < 4; ++mt) {
                    acc2[mt] = __builtin_amdgcn_mfma_f32_16x16x32_bf16(ab[0][mt], p0, zf, 0, 0, 0);
                    acc2[mt] = __builtin_amdgcn_mfma_f32_16x16x32_bf16(ab[1][mt], p1, acc2[mt], 0, 0, 0);
                }

                // unconditional: clamped columns duplicate a real edge (idempotent for max)
#pragma unroll
                for (int mt = 0; mt < 4; ++mt)
#pragma unroll
                    for (int q = 0; q < 4; ++q)
                        rm[mt][q] = fmaxf(rm[mt][q], acc2[mt][q]);
            }
        }

        // ---- reduce-scatter: max over the 16 columns; lane r ends with value r ----
        float k8[8];
#pragma unroll
        for (int j = 0; j < 8; ++j) {
            float lo = rm[j >> 2][j & 3];
            float hv = rm[(j >> 2) + 2][j & 3];
            float tlo = DPPF(lo, 0x128);
            float thi = DPPF(hv, 0x128);
            float own = (r & 8) ? hv : lo;
            float oth = (r & 8) ? thi : tlo;
            k8[j] = fmaxf(own, oth);
        }
        float k4[4];
#pragma unroll
        for (int j = 0; j < 4; ++j) {
            float ta = SWZ4(k8[j]);
            float tb = SWZ4(k8[j + 4]);
            float own = (r & 4) ? k8[j + 4] : k8[j];
            float oth = (r & 4) ? tb : ta;
            k4[j] = fmaxf(own, oth);
        }
        float k2[2];
#pragma unroll
        for (int j = 0; j < 2; ++j) {
            float ta = DPPF(k4[j], 0x4E);
            float tb = DPPF(k4[j + 2], 0x4E);
            float own = (r & 2) ? k4[j + 2] : k4[j];
            float oth = (r & 2) ? tb : ta;
            k2[j] = fmaxf(own, oth);
        }
        float ta = DPPF(k2[0], 0xB1);
        float tb = DPPF(k2[1], 0xB1);
        float vfin = fmaxf((r & 1) ? k2[1] : k2[0], (r & 1) ? tb : ta);

        float o = fmaxf(vfin + b2l, 0.f);  // bias2 + relu (post-max; -inf -> 0 fill)
        if (outb)
            outb[node * 64 + ch] = f32_to_bf16_rne(o);
        else
            outf[node * 64 + ch] = o;
        bsum += o;
        bss += o * o;
    }

    // ---- fused BN stats: block LDS reduce, then 128 global atomics ----
    atomicAdd(&sred[ch], bsum);
    atomicAdd(&sred[64 + ch], bss);
    __syncthreads();
    if (tid < 128) atomicAdd(&statsOut[tid], sred[tid]);
}

// ---------------- batchnorm apply (final layer only) ----------------
__global__ void bn_apply(const float* __restrict__ in, const float* __restrict__ stats,
                         const float* __restrict__ gamma, const float* __restrict__ beta,
                         float* __restrict__ outf, int n4, float invN) {
    int i = blockIdx.x * 256 + threadIdx.x;
    if (i >= n4) return;
    int c0 = (i * 4) & 63;
    f32x4 v = ((const f32x4*)in)[i];
    f32x4 o;
#pragma unroll
    for (int q = 0; q < 4; ++q) {
        int c = c0 + q;
        float mean = stats[c] * invN;
        float var = stats[64 + c] * invN - mean * mean;
        float sc = gamma[c] * rsqrtf(var + EPS);
        o[q] = (v[q] - mean) * sc + beta[c];
    }
    ((f32x4*)outf)[i] = o;
}

extern "C" void kernel_launch(void* const* d_in, const int* in_sizes, int n_in,
                              void* d_out, int out_size, void* d_ws, size_t ws_size,
                              hipStream_t stream) {
    const float* x = (const float*)d_in[0];
    const int* ei = (const int*)d_in[1];
    // d_in[2] = batch (unused, single graph)
    const float* W1a = (const float*)d_in[3];
    const float* b1a = (const float*)d_in[4];
    const float* W1b = (const float*)d_in[5];
    const float* b1b = (const float*)d_in[6];
    const float* gamma1 = (const float*)d_in[7];
    const float* beta1 = (const float*)d_in[8];
    const float* W2a = (const float*)d_in[9];
    const float* b2a = (const float*)d_in[10];
    const float* W2b = (const float*)d_in[11];
    const float* b2b = (const float*)d_in[12];
    const float* gamma2 = (const float*)d_in[13];
    const float* beta2 = (const float*)d_in[14];

    const int N = in_sizes[0] / 64;
    const int E = in_sizes[1] / 2;
    const int NC = N * 64;

    char* ws = (char*)d_ws;
    size_t off = 0;
    auto alloc = [&](size_t bytes) {
        char* p = ws + off;
        off += (bytes + 255) & ~(size_t)255;
        return p;
    };
    unsigned short* xb1 = (unsigned short*)alloc((size_t)NC * 2);  // bf16 x table
    unsigned short* xb2 = (unsigned short*)alloc((size_t)NC * 2);  // bf16 raw h1 table
    unsigned short* pw = (unsigned short*)alloc(24576 * 2);
    float* stats = (float*)alloc(256 * 4);
    float* b2adj = (float*)alloc(64 * 4);
    int* count = (int*)alloc((size_t)N * 4);
    int* offsets = (int*)alloc((size_t)(N + 1) * 4);
    int* cursor = (int*)alloc((size_t)(N + 1) * 4);
    int* ssrc = (int*)alloc((size_t)E * 4);
    int* bsums = (int*)alloc(1024 * 4);

    const int* esrc = ei;
    const int* edst = ei + E;

    // pack stats-independent weights + zero stats/count
    int pgrid = (16640 + N + 255) / 256;
    pack_zero<<<pgrid, 256, 0, stream>>>(W1a, W1b, W2b, pw, stats, count, N);

    // bf16 table + dst histogram
    int n4 = NC / 4;
    int big = max(n4, E);
    cvt_hist<<<(big + 255) / 256, 256, 0, stream>>>(x, xb1, n4, edst, count, E);

    // two-level scan (block-local offsets + bsums; consumers add bsums on the fly)
    int nb = (N + 1023) / 1024;
    scan1<<<nb, 256, 0, stream>>>(count, offsets, cursor, bsums, N);
    scan2<<<1, 256, 0, stream>>>(bsums, offsets, N, nb);
    scatter_kernel<<<(E + 255) / 256, 256, 0, stream>>>(esrc, edst, cursor, bsums, ssrc, E);

    const int egrid = 2048;

    // layer 1: raw post-relu output -> bf16 table xb2 (+ fused BN1 stats)
    edgeconv_sorted<<<egrid, 256, 0, stream>>>(xb1, ssrc, offsets, bsums, pw, pw + 8192,
                                               b1a, b1b, nullptr, xb2, stats, N);

    // fold BN1 into layer-2 first matmul: scaled weights + adjusted bias (16 blocks)
    repack2<<<16, 256, 0, stream>>>(stats, gamma1, beta1, W2a, b2a, pw + 12288, b2adj, 1.0f / N);

    // layer 2: consumes raw h1 table with folded weights -> raw out (+ fused BN2 stats)
    edgeconv_sorted<<<egrid, 256, 0, stream>>>(xb2, ssrc, offsets, bsums, pw + 12288, pw + 20480,
                                               b2adj, b2b, (float*)d_out, nullptr, stats + 128, N);

    // final BN2 normalize in place
    int cgrid = (n4 + 255) / 256;
    bn_apply<<<cgrid, 256, 0, stream>>>((float*)d_out, stats + 128, gamma2, beta2,
                                        (float*)d_out, n4, 1.0f / N);
}

// Round 16
// 255.411 us; speedup vs baseline: 1.3878x; 1.1683x over previous
//
#include <hip/hip_runtime.h>
#include <hip/hip_bf16.h>

typedef float f32x4 __attribute__((ext_vector_type(4)));
typedef short s16x8 __attribute__((ext_vector_type(8)));

#define EPS 1e-5f

__device__ __forceinline__ unsigned short f32_to_bf16_rne(float f) {
    unsigned u = __float_as_uint(f);
    unsigned r = u + 0x7FFFu + ((u >> 16) & 1u);
    return (unsigned short)(r >> 16);
}

// packed 2x bf16 via HW converter (RNE): lo = a, hi = b
__device__ __forceinline__ unsigned cvtpk(float a, float b) {
    unsigned d;
    asm("v_cvt_pk_bf16_f32 %0, %1, %2" : "=v"(d) : "v"(a), "v"(b));
    return d;
}

// DPP helper (compile-time ctrl), all lanes active
#define DPPF(v, c) __int_as_float(__builtin_amdgcn_update_dpp(0, __float_as_int(v), (c), 0xF, 0xF, true))
// ds_swizzle xor4 (BitMode: and=0x1F, or=0, xor=4)
#define SWZ4(v) __int_as_float(__builtin_amdgcn_ds_swizzle(__float_as_int(v), 0x101F))

// ---------------- weight packing (stats-independent ones) + buffer zeroing ----------------
// pw layout (ushort, 4096 each): [0]=W1xi  [4096]=W1xj  [8192]=W1b
//                                [12288]=W2xi' [16384]=W2xj' (filled by repack2)  [20480]=W2b
__global__ void pack_zero(const float* __restrict__ W1a, const float* __restrict__ W1b,
                          const float* __restrict__ W2b, unsigned short* __restrict__ p,
                          float* __restrict__ stats, int* __restrict__ count, int N) {
    int idx = blockIdx.x * 256 + threadIdx.x;
    if (idx < 16384) {
        int m = idx >> 12;
        int t = idx & 4095;
        int j = t & 7;
        int lane = (t >> 3) & 63;
        int mt = (t >> 9) & 3;
        int kc = t >> 11;
        int k = kc * 32 + (lane >> 4) * 8 + j;
        int c = mt * 16 + (lane & 15);
        float v;
        int dst;
        switch (m) {
            case 0: v = W1a[k * 64 + c] - W1a[(k + 64) * 64 + c]; dst = t; break;
            case 1: v = W1a[(k + 64) * 64 + c]; dst = 4096 + t; break;
            case 2: v = W1b[k * 64 + c]; dst = 8192 + t; break;
            default: v = W2b[k * 64 + c]; dst = 20480 + t; break;
        }
        p[dst] = f32_to_bf16_rne(v);
    } else if (idx < 16640) {
        stats[idx - 16384] = 0.f;
    } else if (idx - 16640 < N) {
        count[idx - 16640] = 0;
    }
}

// ---------------- f32 -> bf16 table convert + dst histogram ----------------
__global__ void cvt_hist(const float* __restrict__ in, unsigned short* __restrict__ out, int n4,
                         const int* __restrict__ edst, int* __restrict__ count, int E) {
    int i = blockIdx.x * 256 + threadIdx.x;
    if (i < n4) {
        f32x4 v = ((const f32x4*)in)[i];
        uint2 pr;
        pr.x = cvtpk(v[0], v[1]);
        pr.y = cvtpk(v[2], v[3]);
        *(uint2*)(out + i * 4) = pr;
    }
    if (i < E) atomicAdd(&count[edst[i]], 1);
}

// ---------------- two-level scan: 1024 elems/block ----------------
// scan1 writes BLOCK-LOCAL exclusive offsets into offsets[] and cursor[];
// scan2 makes bsums[] the exclusive block bases and writes offsets[N]=E.
// Consumers add bsums[i>>10] on the fly (scan3 eliminated).
__global__ void scan1(const int* __restrict__ count, int* __restrict__ offsets,
                      int* __restrict__ cursor, int* __restrict__ bsums, int N) {
    __shared__ int sdata[256];
    int t = threadIdx.x;
    int base = blockIdx.x * 1024 + t * 4;
    int4 v = {0, 0, 0, 0};
    if (base + 3 < N) {
        v = *(const int4*)(count + base);
    } else {
        if (base + 0 < N) v.x = count[base + 0];
        if (base + 1 < N) v.y = count[base + 1];
        if (base + 2 < N) v.z = count[base + 2];
    }
    int s = v.x + v.y + v.z + v.w;
    sdata[t] = s;
    __syncthreads();
    for (int off = 1; off < 256; off <<= 1) {
        int u = (t >= off) ? sdata[t - off] : 0;
        __syncthreads();
        sdata[t] += u;
        __syncthreads();
    }
    int excl = sdata[t] - s;
    if (t == 255) bsums[blockIdx.x] = sdata[255];
    int o0 = excl;
    int o1 = o0 + v.x;
    int o2 = o1 + v.y;
    int o3 = o2 + v.z;
    if (base + 0 < N) { offsets[base + 0] = o0; cursor[base + 0] = o0; }
    if (base + 1 < N) { offsets[base + 1] = o1; cursor[base + 1] = o1; }
    if (base + 2 < N) { offsets[base + 2] = o2; cursor[base + 2] = o2; }
    if (base + 3 < N) { offsets[base + 3] = o3; cursor[base + 3] = o3; }
}

__global__ void scan2(int* __restrict__ bsums, int* __restrict__ offsets, int N, int nb) {
    __shared__ int sdata[256];
    int t = threadIdx.x;
    int s = (t < nb) ? bsums[t] : 0;
    sdata[t] = s;
    __syncthreads();
    for (int off = 1; off < 256; off <<= 1) {
        int u = (t >= off) ? sdata[t - off] : 0;
        __syncthreads();
        sdata[t] += u;
        __syncthreads();
    }
    if (t < nb) bsums[t] = sdata[t] - s;  // exclusive block base
    if (t == 255) offsets[N] = sdata[255];  // global total (=E)
}

__global__ void scatter_kernel(const int* __restrict__ esrc, const int* __restrict__ edst,
                               int* __restrict__ cursor, const int* __restrict__ bsums,
                               int* __restrict__ ssrc, int E) {
    int i = blockIdx.x * 256 + threadIdx.x;
    if (i < E) {
        int d = edst[i];
        int pos = atomicAdd(&cursor[d], 1) + bsums[d >> 10];
        ssrc[pos] = esrc[i];
    }
}

// ---------------- BN1 fold: repack layer-2 first-matmul weights + bias ----------------
__global__ void repack2(const float* __restrict__ stats, const float* __restrict__ gamma1,
                        const float* __restrict__ beta1, const float* __restrict__ W2a,
                        const float* __restrict__ b2a, unsigned short* __restrict__ pw2,
                        float* __restrict__ b2adj, float invN) {
    __shared__ float sc[64], sh[64];
    __shared__ float part[4][64];
    int tid = threadIdx.x;
    if (tid < 64) {
        float mean = stats[tid] * invN;
        float var = stats[64 + tid] * invN - mean * mean;
        float s = gamma1[tid] * rsqrtf(var + EPS);
        sc[tid] = s;
        sh[tid] = beta1[tid] - mean * s;
    }
    __syncthreads();
    if (blockIdx.x == 0) {
        int c = tid & 63, sl = tid >> 6;
        float a = 0.f;
#pragma unroll
        for (int kk = 0; kk < 16; ++kk) {
            int k = sl * 16 + kk;
            a += sh[k] * W2a[k * 64 + c];
        }
        part[sl][c] = a;
        __syncthreads();
        if (tid < 64)
            b2adj[tid] = b2a[tid] + part[0][tid] + part[1][tid] + part[2][tid] + part[3][tid];
    }

    for (int e = blockIdx.x * 256 + tid; e < 8192; e += 16 * 256) {
        int m = e >> 12;  // 0: Wxi', 1: Wxj'
        int t = e & 4095;
        int j = t & 7;
        int lane = (t >> 3) & 63;
        int mt = (t >> 9) & 3;
        int kc = t >> 11;
        int k = kc * 32 + (lane >> 4) * 8 + j;
        int c = mt * 16 + (lane & 15);
        float wtop = W2a[k * 64 + c];
        float wbot = W2a[(k + 64) * 64 + c];
        float v = (m == 0) ? sc[k] * (wtop - wbot) : sc[k] * wbot;
        pw2[e] = f32_to_bf16_rne(v);
    }
}

// ---------------- fused EdgeConv on dst-sorted edges (R13 register economy) ----------------
// ALL weight fragments in block-shared LDS (VGPR 60, no spill -- R13-verified);
// any added register state spills (R9/R14/R15 lessons). Offsets are block-local
// + bsums added on the fly (scan3 eliminated).
#define LSTR 72  // LDS row stride in ushorts
__global__ __launch_bounds__(256, 4) void edgeconv_sorted(
    const unsigned short* __restrict__ xb,   // [N][64] bf16 gather table
    const int* __restrict__ ssrc,            // [E] src idx sorted by dst
    const int* __restrict__ offsets,         // [N+1] block-local + offsets[N]=E
    const int* __restrict__ bsums,           // [nb] exclusive block bases
    const unsigned short* __restrict__ pW,   // packed [3][4096]: Wxi, Wxj, Wb
    const float* __restrict__ ba,
    const float* __restrict__ bb,
    float* __restrict__ outf,                // f32 [N][64] or null
    unsigned short* __restrict__ outb,       // bf16 [N][64] or null
    float* __restrict__ statsOut,            // [128] sum/sumsq accumulators
    int N) {
    __shared__ __align__(16) unsigned short lw[12288];          // Wxi|Wxj|Wb
    __shared__ __align__(16) unsigned short xh[4][16 * LSTR];   // xstage/h1 aliased
    __shared__ float sred[128];
    const int tid = threadIdx.x;
    const int w = tid >> 6;
    const int lane = tid & 63;
    const int g = lane >> 4;
    const int r = lane & 15;
    const int srow = lane >> 2;  // staging: row slot this lane serves
    const int schk = lane & 3;   // staging: 16B chunk within row half

    // cooperative weight copy global -> LDS (1536 x 16B)
    for (int i = tid; i < 1536; i += 256)
        ((s16x8*)lw)[i] = ((const s16x8*)pW)[i];
    if (tid < 128) sred[tid] = 0.f;
    __syncthreads();

    const unsigned short* wxi = lw;
    const unsigned short* wxj = lw + 4096;
    const unsigned short* wb = lw + 8192;

    unsigned short* myb = xh[w];
    const int totalWaves = gridDim.x * 4;
    const f32x4 zf = {0.f, 0.f, 0.f, 0.f};

    const int ch = (r >> 2) * 16 + g * 4 + (r & 3);  // this lane's output channel
    const float b2l = bb[ch];
    float bsum = 0.f, bss = 0.f;

    for (int node = blockIdx.x * 4 + w; node < N; node += totalWaves) {
        const int segB = offsets[node] + bsums[node >> 10];
        const int np1 = node + 1;
        const int segE = offsets[np1] + ((np1 < N) ? bsums[np1 >> 10] : 0);

        f32x4 rm[4];
#pragma unroll
        for (int mt = 0; mt < 4; ++mt)
            rm[mt] = (f32x4){-INFINITY, -INFINITY, -INFINITY, -INFINITY};

        if (segB < segE) {
            // first tile prefetch (ssrc + rows) before accxi MFMA work
            int sv = ssrc[min(segB + srow, segE - 1)];
            s16x8 ra = *(const s16x8*)(xb + sv * 64 + schk * 8);
            s16x8 rb = *(const s16x8*)(xb + sv * 64 + 32 + schk * 8);

            // xi-part + bias, once per node (broadcast across the 16 columns)
            s16x8 xi1 = *(const s16x8*)(xb + node * 64 + g * 8);
            s16x8 xi2 = *(const s16x8*)(xb + node * 64 + 32 + g * 8);
            f32x4 accxi[4];
#pragma unroll
            for (int mt = 0; mt < 4; ++mt)
                accxi[mt] = *(const f32x4*)(ba + mt * 16 + g * 4);
#pragma unroll
            for (int mt = 0; mt < 4; ++mt) {
                s16x8 f0 = *(const s16x8*)(wxi + ((0 * 4 + mt) * 64 + lane) * 8);
                accxi[mt] = __builtin_amdgcn_mfma_f32_16x16x32_bf16(f0, xi1, accxi[mt], 0, 0, 0);
                s16x8 f1 = *(const s16x8*)(wxi + ((1 * 4 + mt) * 64 + lane) * 8);
                accxi[mt] = __builtin_amdgcn_mfma_f32_16x16x32_bf16(f1, xi2, accxi[mt], 0, 0, 0);
            }

            for (int t0 = segB; t0 < segE; t0 += 16) {
                // stage prefetched rows (per-wave LDS: in-order, no barrier)
                *(s16x8*)(myb + srow * LSTR + schk * 8) = ra;
                *(s16x8*)(myb + srow * LSTR + 32 + schk * 8) = rb;
                s16x8 xj1 = *(const s16x8*)(myb + r * LSTR + g * 8);
                s16x8 xj2 = *(const s16x8*)(myb + r * LSTR + 32 + g * 8);

                // within-segment prefetch of next tile
                int t1 = t0 + 16;
                if (t1 < segE) {
                    int sv2 = ssrc[min(t1 + srow, segE - 1)];
                    ra = *(const s16x8*)(xb + sv2 * 64 + schk * 8);
                    rb = *(const s16x8*)(xb + sv2 * 64 + 32 + schk * 8);
                }

                // layer 1 (C-init = xi-part + bias); Wxj frags streamed from LDS
                f32x4 acc[4];
#pragma unroll
                for (int mt = 0; mt < 4; ++mt) {
                    s16x8 a0 = *(const s16x8*)(wxj + ((0 * 4 + mt) * 64 + lane) * 8);
                    acc[mt] = __builtin_amdgcn_mfma_f32_16x16x32_bf16(a0, xj1, accxi[mt], 0, 0, 0);
                    s16x8 a1 = *(const s16x8*)(wxj + ((1 * 4 + mt) * 64 + lane) * 8);
                    acc[mt] = __builtin_amdgcn_mfma_f32_16x16x32_bf16(a1, xj2, acc[mt], 0, 0, 0);
                }

                // relu + HW bf16 pack, bounce through LDS (aliased, in-order DS)
#pragma unroll
                for (int mt = 0; mt < 4; ++mt) {
                    uint2 pr;
                    pr.x = cvtpk(fmaxf(acc[mt][0], 0.f), fmaxf(acc[mt][1], 0.f));
                    pr.y = cvtpk(fmaxf(acc[mt][2], 0.f), fmaxf(acc[mt][3], 0.f));
                    *(uint2*)(myb + r * LSTR + mt * 16 + g * 4) = pr;
                }
                s16x8 p0 = *(const s16x8*)(myb + r * LSTR + g * 8);
                s16x8 p1 = *(const s16x8*)(myb + r * LSTR + 32 + g * 8);

                // second matmul; Wb frags streamed from LDS
                f32x4 acc2[4];
#pragma unroll
                for (int mt = 0; mt < 4; ++mt) {
                    s16x8 b0 = *(const s16x8*)(wb + ((0 * 4 + mt) * 64 + lane) * 8);
                    acc2[mt] = __builtin_amdgcn_mfma_f32_16x16x32_bf16(b0, p0, zf, 0, 0, 0);
                    s16x8 b1 = *(const s16x8*)(wb + ((1 * 4 + mt) * 64 + lane) * 8);
                    acc2[mt] = __builtin_amdgcn_mfma_f32_16x16x32_bf16(b1, p1, acc2[mt], 0, 0, 0);
                }

                // unconditional: clamped columns duplicate a real edge (idempotent for max)
#pragma unroll
                for (int mt = 0; mt < 4; ++mt)
#pragma unroll
                    for (int q = 0; q < 4; ++q)
                        rm[mt][q] = fmaxf(rm[mt][q], acc2[mt][q]);
            }
        }

        // ---- reduce-scatter: max over the 16 columns; lane r ends with value r ----
        float k8[8];
#pragma unroll
        for (int j = 0; j < 8; ++j) {
            float lo = rm[j >> 2][j & 3];
            float hv = rm[(j >> 2) + 2][j & 3];
            float tlo = DPPF(lo, 0x128);
            float thi = DPPF(hv, 0x128);
            float own = (r & 8) ? hv : lo;
            float oth = (r & 8) ? thi : tlo;
            k8[j] = fmaxf(own, oth);
        }
        float k4[4];
#pragma unroll
        for (int j = 0; j < 4; ++j) {
            float ta = SWZ4(k8[j]);
            float tb = SWZ4(k8[j + 4]);
            float own = (r & 4) ? k8[j + 4] : k8[j];
            float oth = (r & 4) ? tb : ta;
            k4[j] = fmaxf(own, oth);
        }
        float k2[2];
#pragma unroll
        for (int j = 0; j < 2; ++j) {
            float ta = DPPF(k4[j], 0x4E);
            float tb = DPPF(k4[j + 2], 0x4E);
            float own = (r & 2) ? k4[j + 2] : k4[j];
            float oth = (r & 2) ? tb : ta;
            k2[j] = fmaxf(own, oth);
        }
        float ta = DPPF(k2[0], 0xB1);
        float tb = DPPF(k2[1], 0xB1);
        float vfin = fmaxf((r & 1) ? k2[1] : k2[0], (r & 1) ? tb : ta);

        float o = fmaxf(vfin + b2l, 0.f);  // bias2 + relu (post-max; -inf -> 0 fill)
        if (outb)
            outb[node * 64 + ch] = f32_to_bf16_rne(o);
        else
            outf[node * 64 + ch] = o;
        bsum += o;
        bss += o * o;
    }

    // ---- fused BN stats: block LDS reduce, then 128 global atomics ----
    atomicAdd(&sred[ch], bsum);
    atomicAdd(&sred[64 + ch], bss);
    __syncthreads();
    if (tid < 128) atomicAdd(&statsOut[tid], sred[tid]);
}

// ---------------- batchnorm apply (final layer only) ----------------
__global__ void bn_apply(const float* __restrict__ in, const float* __restrict__ stats,
                         const float* __restrict__ gamma, const float* __restrict__ beta,
                         float* __restrict__ outf, int n4, float invN) {
    int i = blockIdx.x * 256 + threadIdx.x;
    if (i >= n4) return;
    int c0 = (i * 4) & 63;
    f32x4 v = ((const f32x4*)in)[i];
    f32x4 o;
#pragma unroll
    for (int q = 0; q < 4; ++q) {
        int c = c0 + q;
        float mean = stats[c] * invN;
        float var = stats[64 + c] * invN - mean * mean;
        float sc = gamma[c] * rsqrtf(var + EPS);
        o[q] = (v[q] - mean) * sc + beta[c];
    }
    ((f32x4*)outf)[i] = o;
}

extern "C" void kernel_launch(void* const* d_in, const int* in_sizes, int n_in,
                              void* d_out, int out_size, void* d_ws, size_t ws_size,
                              hipStream_t stream) {
    const float* x = (const float*)d_in[0];
    const int* ei = (const int*)d_in[1];
    // d_in[2] = batch (unused, single graph)
    const float* W1a = (const float*)d_in[3];
    const float* b1a = (const float*)d_in[4];
    const float* W1b = (const float*)d_in[5];
    const float* b1b = (const float*)d_in[6];
    const float* gamma1 = (const float*)d_in[7];
    const float* beta1 = (const float*)d_in[8];
    const float* W2a = (const float*)d_in[9];
    const float* b2a = (const float*)d_in[10];
    const float* W2b = (const float*)d_in[11];
    const float* b2b = (const float*)d_in[12];
    const float* gamma2 = (const float*)d_in[13];
    const float* beta2 = (const float*)d_in[14];

    const int N = in_sizes[0] / 64;
    const int E = in_sizes[1] / 2;
    const int NC = N * 64;

    char* ws = (char*)d_ws;
    size_t off = 0;
    auto alloc = [&](size_t bytes) {
        char* p = ws + off;
        off += (bytes + 255) & ~(size_t)255;
        return p;
    };
    unsigned short* xb1 = (unsigned short*)alloc((size_t)NC * 2);  // bf16 x table
    unsigned short* xb2 = (unsigned short*)alloc((size_t)NC * 2);  // bf16 raw h1 table
    unsigned short* pw = (unsigned short*)alloc(24576 * 2);
    float* stats = (float*)alloc(256 * 4);
    float* b2adj = (float*)alloc(64 * 4);
    int* count = (int*)alloc((size_t)N * 4);
    int* offsets = (int*)alloc((size_t)(N + 1) * 4);
    int* cursor = (int*)alloc((size_t)(N + 1) * 4);
    int* ssrc = (int*)alloc((size_t)E * 4);
    int* bsums = (int*)alloc(1024 * 4);

    const int* esrc = ei;
    const int* edst = ei + E;

    // pack stats-independent weights + zero stats/count
    int pgrid = (16640 + N + 255) / 256;
    pack_zero<<<pgrid, 256, 0, stream>>>(W1a, W1b, W2b, pw, stats, count, N);

    // bf16 table + dst histogram
    int n4 = NC / 4;
    int big = max(n4, E);
    cvt_hist<<<(big + 255) / 256, 256, 0, stream>>>(x, xb1, n4, edst, count, E);

    // two-level scan (block-local offsets + bsums; consumers add bsums on the fly)
    int nb = (N + 1023) / 1024;
    scan1<<<nb, 256, 0, stream>>>(count, offsets, cursor, bsums, N);
    scan2<<<1, 256, 0, stream>>>(bsums, offsets, N, nb);
    scatter_kernel<<<(E + 255) / 256, 256, 0, stream>>>(esrc, edst, cursor, bsums, ssrc, E);

    const int egrid = 2048;

    // layer 1: raw post-relu output -> bf16 table xb2 (+ fused BN1 stats)
    edgeconv_sorted<<<egrid, 256, 0, stream>>>(xb1, ssrc, offsets, bsums, pw, b1a, b1b,
                                               nullptr, xb2, stats, N);

    // fold BN1 into layer-2 first matmul: scaled weights + adjusted bias (16 blocks)
    repack2<<<16, 256, 0, stream>>>(stats, gamma1, beta1, W2a, b2a, pw + 12288, b2adj, 1.0f / N);

    // layer 2: consumes raw h1 table with folded weights -> raw out (+ fused BN2 stats)
    edgeconv_sorted<<<egrid, 256, 0, stream>>>(xb2, ssrc, offsets, bsums, pw + 12288, b2adj, b2b,
                                               (float*)d_out, nullptr, stats + 128, N);

    // final BN2 normalize in place
    int cgrid = (n4 + 255) / 256;
    bn_apply<<<cgrid, 256, 0, stream>>>((float*)d_out, stats + 128, gamma2, beta2,
                                        (float*)d_out, n4, 1.0f / N);
}

// Round 17
// 218.671 us; speedup vs baseline: 1.6210x; 1.1680x over previous
//
#include <hip/hip_runtime.h>
#include <hip/hip_bf16.h>

typedef float f32x4 __attribute__((ext_vector_type(4)));
typedef short s16x8 __attribute__((ext_vector_type(8)));

#define EPS 1e-5f

__device__ __forceinline__ unsigned short f32_to_bf16_rne(float f) {
    unsigned u = __float_as_uint(f);
    unsigned r = u + 0x7FFFu + ((u >> 16) & 1u);
    return (unsigned short)(r >> 16);
}

// packed 2x bf16 via HW converter (RNE): lo = a, hi = b
__device__ __forceinline__ unsigned cvtpk(float a, float b) {
    unsigned d;
    asm("v_cvt_pk_bf16_f32 %0, %1, %2" : "=v"(d) : "v"(a), "v"(b));
    return d;
}

// DPP helper (compile-time ctrl), all lanes active
#define DPPF(v, c) __int_as_float(__builtin_amdgcn_update_dpp(0, __float_as_int(v), (c), 0xF, 0xF, true))
// ds_swizzle xor4 (BitMode: and=0x1F, or=0, xor=4)
#define SWZ4(v) __int_as_float(__builtin_amdgcn_ds_swizzle(__float_as_int(v), 0x101F))

// ---------------- weight packing (stats-independent ones) + buffer zeroing ----------------
// pw layout (ushort, 4096 each): [0]=W1xi  [4096]=W1xj  [8192]=W1b
//                                [12288]=W2xi' [16384]=W2xj' (filled by repack2)  [20480]=W2b
__global__ void pack_zero(const float* __restrict__ W1a, const float* __restrict__ W1b,
                          const float* __restrict__ W2b, unsigned short* __restrict__ p,
                          float* __restrict__ stats, int* __restrict__ count, int N) {
    int idx = blockIdx.x * 256 + threadIdx.x;
    if (idx < 16384) {
        int m = idx >> 12;
        int t = idx & 4095;
        int j = t & 7;
        int lane = (t >> 3) & 63;
        int mt = (t >> 9) & 3;
        int kc = t >> 11;
        int k = kc * 32 + (lane >> 4) * 8 + j;
        int c = mt * 16 + (lane & 15);
        float v;
        int dst;
        switch (m) {
            case 0: v = W1a[k * 64 + c] - W1a[(k + 64) * 64 + c]; dst = t; break;
            case 1: v = W1a[(k + 64) * 64 + c]; dst = 4096 + t; break;
            case 2: v = W1b[k * 64 + c]; dst = 8192 + t; break;
            default: v = W2b[k * 64 + c]; dst = 20480 + t; break;
        }
        p[dst] = f32_to_bf16_rne(v);
    } else if (idx < 16640) {
        stats[idx - 16384] = 0.f;
    } else if (idx - 16640 < N) {
        count[idx - 16640] = 0;
    }
}

// ---------------- f32 -> bf16 table convert + dst histogram ----------------
__global__ void cvt_hist(const float* __restrict__ in, unsigned short* __restrict__ out, int n4,
                         const int* __restrict__ edst, int* __restrict__ count, int E) {
    int i = blockIdx.x * 256 + threadIdx.x;
    if (i < n4) {
        f32x4 v = ((const f32x4*)in)[i];
        uint2 pr;
        pr.x = cvtpk(v[0], v[1]);
        pr.y = cvtpk(v[2], v[3]);
        *(uint2*)(out + i * 4) = pr;
    }
    if (i < E) atomicAdd(&count[edst[i]], 1);
}

// ---------------- two-level scan: 1024 elems/block ----------------
// scan1 writes BLOCK-LOCAL exclusive offsets into offsets[] and cursor[];
// scan2 makes bsums[] the exclusive block bases and writes offsets[N]=E.
// Consumers add bsums[i>>10] on the fly.
__global__ void scan1(const int* __restrict__ count, int* __restrict__ offsets,
                      int* __restrict__ cursor, int* __restrict__ bsums, int N) {
    __shared__ int sdata[256];
    int t = threadIdx.x;
    int base = blockIdx.x * 1024 + t * 4;
    int4 v = {0, 0, 0, 0};
    if (base + 3 < N) {
        v = *(const int4*)(count + base);
    } else {
        if (base + 0 < N) v.x = count[base + 0];
        if (base + 1 < N) v.y = count[base + 1];
        if (base + 2 < N) v.z = count[base + 2];
    }
    int s = v.x + v.y + v.z + v.w;
    sdata[t] = s;
    __syncthreads();
    for (int off = 1; off < 256; off <<= 1) {
        int u = (t >= off) ? sdata[t - off] : 0;
        __syncthreads();
        sdata[t] += u;
        __syncthreads();
    }
    int excl = sdata[t] - s;
    if (t == 255) bsums[blockIdx.x] = sdata[255];
    int o0 = excl;
    int o1 = o0 + v.x;
    int o2 = o1 + v.y;
    int o3 = o2 + v.z;
    if (base + 0 < N) { offsets[base + 0] = o0; cursor[base + 0] = o0; }
    if (base + 1 < N) { offsets[base + 1] = o1; cursor[base + 1] = o1; }
    if (base + 2 < N) { offsets[base + 2] = o2; cursor[base + 2] = o2; }
    if (base + 3 < N) { offsets[base + 3] = o3; cursor[base + 3] = o3; }
}

__global__ void scan2(int* __restrict__ bsums, int* __restrict__ offsets, int N, int nb) {
    __shared__ int sdata[256];
    int t = threadIdx.x;
    int s = (t < nb) ? bsums[t] : 0;
    sdata[t] = s;
    __syncthreads();
    for (int off = 1; off < 256; off <<= 1) {
        int u = (t >= off) ? sdata[t - off] : 0;
        __syncthreads();
        sdata[t] += u;
        __syncthreads();
    }
    if (t < nb) bsums[t] = sdata[t] - s;  // exclusive block base
    if (t == 255) offsets[N] = sdata[255];  // global total (=E)
}

__global__ void scatter_kernel(const int* __restrict__ esrc, const int* __restrict__ edst,
                               int* __restrict__ cursor, const int* __restrict__ bsums,
                               int* __restrict__ ssrc, int E) {
    int i = blockIdx.x * 256 + threadIdx.x;
    if (i < E) {
        int d = edst[i];
        int pos = atomicAdd(&cursor[d], 1) + bsums[d >> 10];
        ssrc[pos] = esrc[i];
    }
}

// ---------------- BN1 fold: repack layer-2 first-matmul weights + bias ----------------
__global__ void repack2(const float* __restrict__ stats, const float* __restrict__ gamma1,
                        const float* __restrict__ beta1, const float* __restrict__ W2a,
                        const float* __restrict__ b2a, unsigned short* __restrict__ pw2,
                        float* __restrict__ b2adj, float invN) {
    __shared__ float sc[64], sh[64];
    __shared__ float part[4][64];
    int tid = threadIdx.x;
    if (tid < 64) {
        float mean = stats[tid] * invN;
        float var = stats[64 + tid] * invN - mean * mean;
        float s = gamma1[tid] * rsqrtf(var + EPS);
        sc[tid] = s;
        sh[tid] = beta1[tid] - mean * s;
    }
    __syncthreads();
    if (blockIdx.x == 0) {
        int c = tid & 63, sl = tid >> 6;
        float a = 0.f;
#pragma unroll
        for (int kk = 0; kk < 16; ++kk) {
            int k = sl * 16 + kk;
            a += sh[k] * W2a[k * 64 + c];
        }
        part[sl][c] = a;
        __syncthreads();
        if (tid < 64)
            b2adj[tid] = b2a[tid] + part[0][tid] + part[1][tid] + part[2][tid] + part[3][tid];
    }

    for (int e = blockIdx.x * 256 + tid; e < 8192; e += 16 * 256) {
        int m = e >> 12;  // 0: Wxi', 1: Wxj'
        int t = e & 4095;
        int j = t & 7;
        int lane = (t >> 3) & 63;
        int mt = (t >> 9) & 3;
        int kc = t >> 11;
        int k = kc * 32 + (lane >> 4) * 8 + j;
        int c = mt * 16 + (lane & 15);
        float wtop = W2a[k * 64 + c];
        float wbot = W2a[(k + 64) * 64 + c];
        float v = (m == 0) ? sc[k] * (wtop - wbot) : sc[k] * wbot;
        pw2[e] = f32_to_bf16_rne(v);
    }
}

// ---------------- fused EdgeConv on dst-sorted edges (occupancy-max geometry) ----------------
// 512-thread blocks (8 waves): per-tile weights Wxj|Wb in LDS amortized over 8 waves;
// per-NODE weight Wxi read straight from global (8KB, L1-hot, coalesced).
// LDS/block = 16KB + 8x2.25KB + 0.5KB = 35.3KB -> 4 blocks/CU -> 32 waves/CU cap
// (2x R13's 16). VGPR economy identical to R13 (60, no spill).
#define LSTR 72  // LDS row stride in ushorts
__global__ __launch_bounds__(512, 4) void edgeconv_sorted(
    const unsigned short* __restrict__ xb,    // [N][64] bf16 gather table
    const int* __restrict__ ssrc,             // [E] src idx sorted by dst
    const int* __restrict__ offsets,          // [N+1] block-local + offsets[N]=E
    const int* __restrict__ bsums,            // [nb] exclusive block bases
    const unsigned short* __restrict__ pWxi,  // packed [4096]: Wxi (global, L1-hot)
    const unsigned short* __restrict__ pWjb,  // packed [2][4096]: Wxj, Wb
    const float* __restrict__ ba,
    const float* __restrict__ bb,
    float* __restrict__ outf,                 // f32 [N][64] or null
    unsigned short* __restrict__ outb,        // bf16 [N][64] or null
    float* __restrict__ statsOut,             // [128] sum/sumsq accumulators
    int N) {
    __shared__ __align__(16) unsigned short lw[8192];           // Wxj|Wb
    __shared__ __align__(16) unsigned short xh[8][16 * LSTR];   // per-wave xstage/h1
    __shared__ float sred[128];
    const int tid = threadIdx.x;
    const int w = tid >> 6;      // 0..7
    const int lane = tid & 63;
    const int g = lane >> 4;
    const int r = lane & 15;
    const int srow = lane >> 2;  // staging: row slot this lane serves
    const int schk = lane & 3;   // staging: 16B chunk within row half

    // cooperative weight copy global -> LDS (1024 x 16B over 512 threads)
    for (int i = tid; i < 1024; i += 512)
        ((s16x8*)lw)[i] = ((const s16x8*)pWjb)[i];
    if (tid < 128) sred[tid] = 0.f;
    __syncthreads();

    const unsigned short* wxj = lw;
    const unsigned short* wb = lw + 4096;

    unsigned short* myb = xh[w];
    const int totalWaves = gridDim.x * 8;
    const f32x4 zf = {0.f, 0.f, 0.f, 0.f};

    const int ch = (r >> 2) * 16 + g * 4 + (r & 3);  // this lane's output channel
    const float b2l = bb[ch];
    float bsum = 0.f, bss = 0.f;

    for (int node = blockIdx.x * 8 + w; node < N; node += totalWaves) {
        const int segB = offsets[node] + bsums[node >> 10];
        const int np1 = node + 1;
        const int segE = offsets[np1] + ((np1 < N) ? bsums[np1 >> 10] : 0);

        f32x4 rm[4];
#pragma unroll
        for (int mt = 0; mt < 4; ++mt)
            rm[mt] = (f32x4){-INFINITY, -INFINITY, -INFINITY, -INFINITY};

        if (segB < segE) {
            // first tile prefetch (ssrc + rows) before accxi MFMA work
            int sv = ssrc[min(segB + srow, segE - 1)];
            s16x8 ra = *(const s16x8*)(xb + sv * 64 + schk * 8);
            s16x8 rb = *(const s16x8*)(xb + sv * 64 + 32 + schk * 8);

            // xi-part + bias, once per node; Wxi fragments straight from global (L1)
            s16x8 xi1 = *(const s16x8*)(xb + node * 64 + g * 8);
            s16x8 xi2 = *(const s16x8*)(xb + node * 64 + 32 + g * 8);
            f32x4 accxi[4];
#pragma unroll
            for (int mt = 0; mt < 4; ++mt)
                accxi[mt] = *(const f32x4*)(ba + mt * 16 + g * 4);
#pragma unroll
            for (int mt = 0; mt < 4; ++mt) {
                s16x8 f0 = *(const s16x8*)(pWxi + ((0 * 4 + mt) * 64 + lane) * 8);
                accxi[mt] = __builtin_amdgcn_mfma_f32_16x16x32_bf16(f0, xi1, accxi[mt], 0, 0, 0);
                s16x8 f1 = *(const s16x8*)(pWxi + ((1 * 4 + mt) * 64 + lane) * 8);
                accxi[mt] = __builtin_amdgcn_mfma_f32_16x16x32_bf16(f1, xi2, accxi[mt], 0, 0, 0);
            }

            for (int t0 = segB; t0 < segE; t0 += 16) {
                // stage prefetched rows (per-wave LDS: in-order, no barrier)
                *(s16x8*)(myb + srow * LSTR + schk * 8) = ra;
                *(s16x8*)(myb + srow * LSTR + 32 + schk * 8) = rb;
                s16x8 xj1 = *(const s16x8*)(myb + r * LSTR + g * 8);
                s16x8 xj2 = *(const s16x8*)(myb + r * LSTR + 32 + g * 8);

                // within-segment prefetch of next tile
                int t1 = t0 + 16;
                if (t1 < segE) {
                    int sv2 = ssrc[min(t1 + srow, segE - 1)];
                    ra = *(const s16x8*)(xb + sv2 * 64 + schk * 8);
                    rb = *(const s16x8*)(xb + sv2 * 64 + 32 + schk * 8);
                }

                // layer 1 (C-init = xi-part + bias); Wxj frags streamed from LDS
                f32x4 acc[4];
#pragma unroll
                for (int mt = 0; mt < 4; ++mt) {
                    s16x8 a0 = *(const s16x8*)(wxj + ((0 * 4 + mt) * 64 + lane) * 8);
                    acc[mt] = __builtin_amdgcn_mfma_f32_16x16x32_bf16(a0, xj1, accxi[mt], 0, 0, 0);
                    s16x8 a1 = *(const s16x8*)(wxj + ((1 * 4 + mt) * 64 + lane) * 8);
                    acc[mt] = __builtin_amdgcn_mfma_f32_16x16x32_bf16(a1, xj2, acc[mt], 0, 0, 0);
                }

                // relu + HW bf16 pack, bounce through LDS (aliased, in-order DS)
#pragma unroll
                for (int mt = 0; mt < 4; ++mt) {
                    uint2 pr;
                    pr.x = cvtpk(fmaxf(acc[mt][0], 0.f), fmaxf(acc[mt][1], 0.f));
                    pr.y = cvtpk(fmaxf(acc[mt][2], 0.f), fmaxf(acc[mt][3], 0.f));
                    *(uint2*)(myb + r * LSTR + mt * 16 + g * 4) = pr;
                }
                s16x8 p0 = *(const s16x8*)(myb + r * LSTR + g * 8);
                s16x8 p1 = *(const s16x8*)(myb + r * LSTR + 32 + g * 8);

                // second matmul; Wb frags streamed from LDS
                f32x4 acc2[4];
#pragma unroll
                for (int mt = 0; mt < 4; ++mt) {
                    s16x8 b0 = *(const s16x8*)(wb + ((0 * 4 + mt) * 64 + lane) * 8);
                    acc2[mt] = __builtin_amdgcn_mfma_f32_16x16x32_bf16(b0, p0, zf, 0, 0, 0);
                    s16x8 b1 = *(const s16x8*)(wb + ((1 * 4 + mt) * 64 + lane) * 8);
                    acc2[mt] = __builtin_amdgcn_mfma_f32_16x16x32_bf16(b1, p1, acc2[mt], 0, 0, 0);
                }

                // unconditional: clamped columns duplicate a real edge (idempotent for max)
#pragma unroll
                for (int mt = 0; mt < 4; ++mt)
#pragma unroll
                    for (int q = 0; q < 4; ++q)
                        rm[mt][q] = fmaxf(rm[mt][q], acc2[mt][q]);
            }
        }

        // ---- reduce-scatter: max over the 16 columns; lane r ends with value r ----
        float k8[8];
#pragma unroll
        for (int j = 0; j < 8; ++j) {
            float lo = rm[j >> 2][j & 3];
            float hv = rm[(j >> 2) + 2][j & 3];
            float tlo = DPPF(lo, 0x128);
            float thi = DPPF(hv, 0x128);
            float own = (r & 8) ? hv : lo;
            float oth = (r & 8) ? thi : tlo;
            k8[j] = fmaxf(own, oth);
        }
        float k4[4];
#pragma unroll
        for (int j = 0; j < 4; ++j) {
            float ta = SWZ4(k8[j]);
            float tb = SWZ4(k8[j + 4]);
            float own = (r & 4) ? k8[j + 4] : k8[j];
            float oth = (r & 4) ? tb : ta;
            k4[j] = fmaxf(own, oth);
        }
        float k2[2];
#pragma unroll
        for (int j = 0; j < 2; ++j) {
            float ta = DPPF(k4[j], 0x4E);
            float tb = DPPF(k4[j + 2], 0x4E);
            float own = (r & 2) ? k4[j + 2] : k4[j];
            float oth = (r & 2) ? tb : ta;
            k2[j] = fmaxf(own, oth);
        }
        float ta = DPPF(k2[0], 0xB1);
        float tb = DPPF(k2[1], 0xB1);
        float vfin = fmaxf((r & 1) ? k2[1] : k2[0], (r & 1) ? tb : ta);

        float o = fmaxf(vfin + b2l, 0.f);  // bias2 + relu (post-max; -inf -> 0 fill)
        if (outb)
            outb[node * 64 + ch] = f32_to_bf16_rne(o);
        else
            outf[node * 64 + ch] = o;
        bsum += o;
        bss += o * o;
    }

    // ---- fused BN stats: block LDS reduce, then 128 global atomics ----
    atomicAdd(&sred[ch], bsum);
    atomicAdd(&sred[64 + ch], bss);
    __syncthreads();
    if (tid < 128) atomicAdd(&statsOut[tid], sred[tid]);
}

// ---------------- batchnorm apply (final layer only) ----------------
__global__ void bn_apply(const float* __restrict__ in, const float* __restrict__ stats,
                         const float* __restrict__ gamma, const float* __restrict__ beta,
                         float* __restrict__ outf, int n4, float invN) {
    int i = blockIdx.x * 256 + threadIdx.x;
    if (i >= n4) return;
    int c0 = (i * 4) & 63;
    f32x4 v = ((const f32x4*)in)[i];
    f32x4 o;
#pragma unroll
    for (int q = 0; q < 4; ++q) {
        int c = c0 + q;
        float mean = stats[c] * invN;
        float var = stats[64 + c] * invN - mean * mean;
        float sc = gamma[c] * rsqrtf(var + EPS);
        o[q] = (v[q] - mean) * sc + beta[c];
    }
    ((f32x4*)outf)[i] = o;
}

extern "C" void kernel_launch(void* const* d_in, const int* in_sizes, int n_in,
                              void* d_out, int out_size, void* d_ws, size_t ws_size,
                              hipStream_t stream) {
    const float* x = (const float*)d_in[0];
    const int* ei = (const int*)d_in[1];
    // d_in[2] = batch (unused, single graph)
    const float* W1a = (const float*)d_in[3];
    const float* b1a = (const float*)d_in[4];
    const float* W1b = (const float*)d_in[5];
    const float* b1b = (const float*)d_in[6];
    const float* gamma1 = (const float*)d_in[7];
    const float* beta1 = (const float*)d_in[8];
    const float* W2a = (const float*)d_in[9];
    const float* b2a = (const float*)d_in[10];
    const float* W2b = (const float*)d_in[11];
    const float* b2b = (const float*)d_in[12];
    const float* gamma2 = (const float*)d_in[13];
    const float* beta2 = (const float*)d_in[14];

    const int N = in_sizes[0] / 64;
    const int E = in_sizes[1] / 2;
    const int NC = N * 64;

    char* ws = (char*)d_ws;
    size_t off = 0;
    auto alloc = [&](size_t bytes) {
        char* p = ws + off;
        off += (bytes + 255) & ~(size_t)255;
        return p;
    };
    unsigned short* xb1 = (unsigned short*)alloc((size_t)NC * 2);  // bf16 x table
    unsigned short* xb2 = (unsigned short*)alloc((size_t)NC * 2);  // bf16 raw h1 table
    unsigned short* pw = (unsigned short*)alloc(24576 * 2);
    float* stats = (float*)alloc(256 * 4);
    float* b2adj = (float*)alloc(64 * 4);
    int* count = (int*)alloc((size_t)N * 4);
    int* offsets = (int*)alloc((size_t)(N + 1) * 4);
    int* cursor = (int*)alloc((size_t)(N + 1) * 4);
    int* ssrc = (int*)alloc((size_t)E * 4);
    int* bsums = (int*)alloc(1024 * 4);

    const int* esrc = ei;
    const int* edst = ei + E;

    // pack stats-independent weights + zero stats/count
    int pgrid = (16640 + N + 255) / 256;
    pack_zero<<<pgrid, 256, 0, stream>>>(W1a, W1b, W2b, pw, stats, count, N);

    // bf16 table + dst histogram
    int n4 = NC / 4;
    int big = max(n4, E);
    cvt_hist<<<(big + 255) / 256, 256, 0, stream>>>(x, xb1, n4, edst, count, E);

    // two-level scan (block-local offsets + bsums; consumers add bsums on the fly)
    int nb = (N + 1023) / 1024;
    scan1<<<nb, 256, 0, stream>>>(count, offsets, cursor, bsums, N);
    scan2<<<1, 256, 0, stream>>>(bsums, offsets, N, nb);
    scatter_kernel<<<(E + 255) / 256, 256, 0, stream>>>(esrc, edst, cursor, bsums, ssrc, E);

    const int egrid = 1024;  // 512-thread blocks, 8 waves each

    // layer 1: raw post-relu output -> bf16 table xb2 (+ fused BN1 stats)
    edgeconv_sorted<<<egrid, 512, 0, stream>>>(xb1, ssrc, offsets, bsums, pw, pw + 4096,
                                               b1a, b1b, nullptr, xb2, stats, N);

    // fold BN1 into layer-2 first matmul: scaled weights + adjusted bias (16 blocks)
    repack2<<<16, 256, 0, stream>>>(stats, gamma1, beta1, W2a, b2a, pw + 12288, b2adj, 1.0f / N);

    // layer 2: consumes raw h1 table with folded weights -> raw out (+ fused BN2 stats)
    edgeconv_sorted<<<egrid, 512, 0, stream>>>(xb2, ssrc, offsets, bsums, pw + 12288, pw + 16384,
                                               b2adj, b2b, (float*)d_out, nullptr, stats + 128, N);

    // final BN2 normalize in place
    int cgrid = (n4 + 255) / 256;
    bn_apply<<<cgrid, 256, 0, stream>>>((float*)d_out, stats + 128, gamma2, beta2,
                                        (float*)d_out, n4, 1.0f / N);
}